// Round 6
// baseline (74.764 us; speedup 1.0000x reference)
//
#include <hip/hip_runtime.h>

// Binary successive-approximation encoder:
//   v = clip(x,0,1); bit i of floor(v*2^n) (clamped to 2^n-1) reproduces the
//   reference's successive subtraction exactly (all pow2 ops exact in fp32).
// x: [16,1024,512] f32 -> out: [16,1024,n_bits,512] f32.
//
// R6: COARSEN READ/WRITE INTERLEAVE. Fill (pure write) hits 6.9 TB/s at 10%
// occupancy; we sat at 5.0 TB/s with 1KB-read : 5KB-write fine-grain mixing.
// Hypothesis: DRAM read<->write bus turnarounds. Each block now covers 16
// consecutive rows: phase 1 = 16 independent loads per thread (16KB read
// burst/wave), phase 2 = up to 80 stores per thread (80KB write burst/wave),
// still globally monotone within each row group. Traffic unchanged.
//
// Thread map within a row (same as R5): 256 thr = 2 x 128 float4;
// c4 = tid&127 picks the input float4, bit0 = tid>>7 picks bit parity, so
// output float4 slot (k*256+tid) == (2k+bit0)*128 + c4 — byte-sequential in k.

#define C_DIM 512
#define C4    128   // C_DIM / 4
#define ROWS   16   // rows per block

typedef float f32x4 __attribute__((ext_vector_type(4)));

__global__ __launch_bounds__(256) void binenc_kernel(const float* __restrict__ x,
                                                     const int* __restrict__ n_bits_p,
                                                     float* __restrict__ out,
                                                     int n_rows) {
    const int n_bits = *n_bits_p;
    const float scale = (float)(1u << n_bits);
    const int   maxq  = (1 << n_bits) - 1;

    const int tid  = threadIdx.x;
    const int c4   = tid & (C4 - 1);
    const int bit0 = tid >> 7;
    const int g    = blockIdx.x * ROWS;

    if (g + ROWS <= n_rows) {
        // ---- fast path: full 16-row group ----
        // Phase 1: batch all reads (independent -> compiler issues back-to-back).
        f32x4 xv[ROWS];
#pragma unroll
        for (int r = 0; r < ROWS; ++r)
            xv[r] = reinterpret_cast<const f32x4*>(x)[(size_t)(g + r) * C4 + c4];

        // Phase 2: long write burst, rows in address order.
#pragma unroll
        for (int r = 0; r < ROWS; ++r) {
            int q[4];
#pragma unroll
            for (int j = 0; j < 4; ++j) {
                float v  = fminf(fmaxf(xv[r][j], 0.0f), 1.0f);  // jnp.clip, exact
                int   qi = (int)(v * scale);                    // exact pow2 scale+trunc
                q[j] = qi > maxq ? maxq : qi;                   // v==1.0 -> all bits
            }
            f32x4* rowbase = reinterpret_cast<f32x4*>(out) + (size_t)(g + r) * n_bits * C4;
#pragma unroll 5
            for (int k = 0; 2 * k + bit0 < n_bits; ++k) {
                const int sh = n_bits - 1 - (2 * k + bit0);
                f32x4 s;
#pragma unroll
                for (int j = 0; j < 4; ++j)
                    s[j] = (float)((q[j] >> sh) & 1);
                rowbase[k * 256 + tid] = s;
            }
        }
    } else {
        // ---- guarded tail (n_rows not a multiple of ROWS) ----
        for (int r = 0; r < ROWS && g + r < n_rows; ++r) {
            const f32x4 xv = reinterpret_cast<const f32x4*>(x)[(size_t)(g + r) * C4 + c4];
            int q[4];
#pragma unroll
            for (int j = 0; j < 4; ++j) {
                float v  = fminf(fmaxf(xv[j], 0.0f), 1.0f);
                int   qi = (int)(v * scale);
                q[j] = qi > maxq ? maxq : qi;
            }
            f32x4* rowbase = reinterpret_cast<f32x4*>(out) + (size_t)(g + r) * n_bits * C4;
            for (int k = 0; 2 * k + bit0 < n_bits; ++k) {
                const int sh = n_bits - 1 - (2 * k + bit0);
                f32x4 s;
#pragma unroll
                for (int j = 0; j < 4; ++j)
                    s[j] = (float)((q[j] >> sh) & 1);
                rowbase[k * 256 + tid] = s;
            }
        }
    }
}

extern "C" void kernel_launch(void* const* d_in, const int* in_sizes, int n_in,
                              void* d_out, int out_size, void* d_ws, size_t ws_size,
                              hipStream_t stream) {
    const float* x        = (const float*)d_in[0];
    const int*   n_bits_p = (const int*)d_in[1];
    float*       out      = (float*)d_out;

    const int n_rows = in_sizes[0] / C_DIM;            // 16*1024 = 16384
    const int grid   = (n_rows + ROWS - 1) / ROWS;     // 1024 blocks
    const int block  = 256;

    binenc_kernel<<<grid, block, 0, stream>>>(x, n_bits_p, out, n_rows);
}